// Round 1
// baseline (1082.138 us; speedup 1.0000x reference)
//
#include <hip/hip_runtime.h>
#include <hip/hip_bf16.h>

// Problem constants (fixed by the reference setup)
#define B_ 64
#define T_ 1024
#define I_ 64
#define H_ 512
#define R_ 8
#define O_ 64

// fast tanh: tanh(x) = 1 - 2/(exp2(2*log2(e)*x)+1); well-behaved at +-inf
__device__ __forceinline__ float ftanh(float x) {
    float e = __builtin_amdgcn_exp2f(x * 2.8853900817779268f); // 2*log2(e)
    return 1.0f - 2.0f * __builtin_amdgcn_rcpf(e + 1.0f);
}

// ---------------------------------------------------------------------------
// Kernel 1: inp[b,t,h] = sum_i u[b,t,i]*W_in[h,i] + b_in[h]
// written into the traj region of d_out (scan overwrites slot t after reading)
// grid: (T/64, H/128, B), block 256. LDS-tiled fp32.
// ---------------------------------------------------------------------------
__global__ __launch_bounds__(256) void inp_gemm(
    const float* __restrict__ u, const float* __restrict__ W_in,
    const float* __restrict__ b_in, float* __restrict__ inp)
{
    __shared__ float4 su4[64 * 17];   // u tile [64 t][16 f4], row pad 17
    __shared__ float4 sw4[128 * 17];  // W tile [128 h][16 f4], row pad 17

    const int tid = threadIdx.x;
    const int t0 = blockIdx.x * 64;
    const int h0 = blockIdx.y * 128;
    const int b  = blockIdx.z;

    const float4* usrc = (const float4*)(u + (size_t)(b * T_ + t0) * I_);
    const float4* wsrc = (const float4*)(W_in + (size_t)h0 * I_);

    #pragma unroll
    for (int k = tid; k < 64 * 16; k += 256)
        su4[(k >> 4) * 17 + (k & 15)] = usrc[k];
    #pragma unroll
    for (int k = tid; k < 128 * 16; k += 256)
        sw4[(k >> 4) * 17 + (k & 15)] = wsrc[k];
    __syncthreads();

    const int tg = tid >> 4;   // 16 groups -> 4 t each
    const int hi = tid & 15;   // h = h0 + hi + 16*c

    float acc[4][8];
    #pragma unroll
    for (int a = 0; a < 4; ++a)
        #pragma unroll
        for (int c = 0; c < 8; ++c) acc[a][c] = 0.0f;

    #pragma unroll
    for (int i4 = 0; i4 < 16; ++i4) {
        float4 uv[4], wv[8];
        #pragma unroll
        for (int a = 0; a < 4; ++a) uv[a] = su4[(tg * 4 + a) * 17 + i4];
        #pragma unroll
        for (int c = 0; c < 8; ++c) wv[c] = sw4[(hi + 16 * c) * 17 + i4];
        #pragma unroll
        for (int a = 0; a < 4; ++a)
            #pragma unroll
            for (int c = 0; c < 8; ++c)
                acc[a][c] += uv[a].x * wv[c].x + uv[a].y * wv[c].y +
                             uv[a].z * wv[c].z + uv[a].w * wv[c].w;
    }

    #pragma unroll
    for (int c = 0; c < 8; ++c) {
        float bi = b_in[h0 + hi + 16 * c];
        #pragma unroll
        for (int a = 0; a < 4; ++a)
            inp[(size_t)(b * T_ + t0 + tg * 4 + a) * H_ + h0 + hi + 16 * c] =
                acc[a][c] + bi;
    }
}

// ---------------------------------------------------------------------------
// Kernel 2: sequential scan. One block per batch (64 blocks x 256 threads).
// Each thread owns h = 2*tid, 2*tid+1. Weights in registers, scale folded
// into L. Fold-butterfly reduce (17 shuffles) + 2-barrier cross-wave combine.
// Distance-2 prefetch of noise/inp via 3-slot register rotation.
// ---------------------------------------------------------------------------
__device__ __forceinline__ void unpack8(const float4* p, float* d) {
    float4 a = p[0], b = p[1];
    d[0] = a.x; d[1] = a.y; d[2] = a.z; d[3] = a.w;
    d[4] = b.x; d[5] = b.y; d[6] = b.z; d[7] = b.w;
}

__global__ __launch_bounds__(256) void scan_kernel(
    const float* __restrict__ noise, const float* __restrict__ x0,
    const float* __restrict__ Lm, const float* __restrict__ Mm,
    const float* __restrict__ Nm,
    float* __restrict__ traj, float* __restrict__ xlast)
{
    const int tid  = threadIdx.x;
    const int b    = blockIdx.x;
    const int h0   = tid * 2;
    const int lane = tid & 63;
    const int wv   = tid >> 6;
    // output index held by this lane after the fold = bitrev4(lane&15)
    const int jlane = ((lane & 1) << 3) | ((lane & 2) << 1) |
                      ((lane & 4) >> 1) | ((lane & 8) >> 3);

    float m0[8], m1[8], n0[8], n1[8], l0[8], l1[8];
    unpack8((const float4*)(Mm + (size_t)h0 * R_), m0);
    unpack8((const float4*)(Mm + (size_t)h0 * R_) + 2, m1);
    unpack8((const float4*)(Nm + (size_t)h0 * R_), n0);
    unpack8((const float4*)(Nm + (size_t)h0 * R_) + 2, n1);
    unpack8((const float4*)(Lm + (size_t)h0 * R_), l0);
    unpack8((const float4*)(Lm + (size_t)h0 * R_) + 2, l1);
    const float scale = 1.0f / ((float)H_ * (float)H_);
    #pragma unroll
    for (int j = 0; j < 8; ++j) { l0[j] *= scale; l1[j] *= scale; }

    float2 xv = *(const float2*)(x0 + (size_t)b * H_ + h0);

    const float2* nsrc = (const float2*)noise + (size_t)b * (H_ / 2) + tid; // +t*16384
    float2* tptr = (float2*)traj + (size_t)b * (T_ * H_ / 2) + tid;         // +t*256

    __shared__ __align__(16) float red[64];
    __shared__ __align__(16) float fin[16];

    float2 ib[3], nb[3];
    ib[0] = tptr[0];       nb[0] = nsrc[0];
    ib[1] = tptr[256];     nb[1] = nsrc[16384];

    auto step = [&](int t, int cur, int nxt) {
        if (t + 2 < T_) {
            ib[nxt] = tptr[(t + 2) * 256];
            nb[nxt] = nsrc[(size_t)(t + 2) * 16384];
        }
        const float2 inp = ib[cur], nz = nb[cur];
        const float r0 = ftanh(xv.x), r1 = ftanh(xv.y);

        float p[16];
        #pragma unroll
        for (int j = 0; j < 8; ++j) p[j]     = r0 * m0[j] + r1 * m1[j];
        #pragma unroll
        for (int j = 0; j < 8; ++j) p[8 + j] = r0 * n0[j] + r1 * n1[j];

        // fold-butterfly: 16 values over lanes 0..15 (within each 16-group)
        #define FOLD(MASK, NV)                                              \
        {                                                                   \
            const bool hb = (lane & MASK) != 0;                             \
            _Pragma("unroll")                                               \
            for (int k = 0; k < NV; ++k) {                                  \
                float send = hb ? p[k] : p[k + NV];                         \
                float recv = __shfl_xor(send, MASK, 64);                    \
                p[k] = (hb ? p[k + NV] : p[k]) + recv;                      \
            }                                                               \
        }
        FOLD(1, 8) FOLD(2, 4) FOLD(4, 2) FOLD(8, 1)
        #undef FOLD

        float s = p[0];
        s += __shfl_xor(s, 16, 64);
        s += __shfl_xor(s, 32, 64);
        if (lane < 16) red[wv * 16 + jlane] = s;
        __syncthreads();
        if (tid < 16)
            fin[tid] = red[tid] + red[tid + 16] + red[tid + 32] + red[tid + 48];
        __syncthreads();

        const float4 fA = *(const float4*)(fin + 0);
        const float4 fB = *(const float4*)(fin + 4);
        const float4 fC = *(const float4*)(fin + 8);
        const float4 fD = *(const float4*)(fin + 12);
        float prod[8] = { fA.x * fC.x, fA.y * fC.y, fA.z * fC.z, fA.w * fC.w,
                          fB.x * fD.x, fB.y * fD.y, fB.z * fD.z, fB.w * fD.w };

        float rec0 = 0.0f, rec1 = 0.0f;
        #pragma unroll
        for (int j = 0; j < 8; ++j) { rec0 += l0[j] * prod[j]; rec1 += l1[j] * prod[j]; }

        xv.x = 0.8f * xv.x + 0.05f * nz.x + 0.2f * rec0 + 0.2f * inp.x;
        xv.y = 0.8f * xv.y + 0.05f * nz.y + 0.2f * rec1 + 0.2f * inp.y;
        tptr[t * 256] = xv;
    };

    for (int t = 0; t < 1021; t += 3) {  // 341 triples: steps 0..1022
        step(t,     0, 2);
        step(t + 1, 1, 0);
        step(t + 2, 2, 1);
    }
    step(1023, 0, 2);  // tail (1023 % 3 == 0); prefetch guarded off

    *(float2*)(xlast + (size_t)b * H_ + h0) = xv;
}

// ---------------------------------------------------------------------------
// Kernel 3: output[b,t,o] = sum_h tanh(traj[b,t,h])*W_out[o,h] + b_out[o]
// grid: (T/64, B), block 256. K=512 in 8 chunks of 64; tanh fused in staging.
// ---------------------------------------------------------------------------
__global__ __launch_bounds__(256) void out_gemm(
    const float* __restrict__ traj, const float* __restrict__ W_out,
    const float* __restrict__ b_out, float* __restrict__ out)
{
    __shared__ float4 sa4[64 * 17];  // tanh(traj) tile [64 t][16 f4]
    __shared__ float4 sb4[64 * 17];  // W_out tile [64 o][16 f4]

    const int tid = threadIdx.x;
    const int t0 = blockIdx.x * 64;
    const int b  = blockIdx.y;
    const int tg = tid >> 4, oi = tid & 15;

    float acc[4][4];
    #pragma unroll
    for (int a = 0; a < 4; ++a)
        #pragma unroll
        for (int c = 0; c < 4; ++c) acc[a][c] = 0.0f;

    const float4* tsrc = (const float4*)(traj + (size_t)(b * T_ + t0) * H_);
    const float4* wsrc = (const float4*)W_out;

    for (int hc = 0; hc < 8; ++hc) {
        const int hb4 = hc * 16;  // f4 offset within a 512-float row
        #pragma unroll
        for (int j = 0; j < 4; ++j) {
            int k = tid + 256 * j;
            int row = k >> 4, col = k & 15;
            float4 v = tsrc[(size_t)row * 128 + hb4 + col];
            v.x = ftanh(v.x); v.y = ftanh(v.y); v.z = ftanh(v.z); v.w = ftanh(v.w);
            sa4[row * 17 + col] = v;
            sb4[row * 17 + col] = wsrc[(size_t)row * 128 + hb4 + col];
        }
        __syncthreads();
        #pragma unroll
        for (int i4 = 0; i4 < 16; ++i4) {
            float4 av[4], bv[4];
            #pragma unroll
            for (int a = 0; a < 4; ++a) av[a] = sa4[(tg * 4 + a) * 17 + i4];
            #pragma unroll
            for (int c = 0; c < 4; ++c) bv[c] = sb4[(oi + 16 * c) * 17 + i4];
            #pragma unroll
            for (int a = 0; a < 4; ++a)
                #pragma unroll
                for (int c = 0; c < 4; ++c)
                    acc[a][c] += av[a].x * bv[c].x + av[a].y * bv[c].y +
                                 av[a].z * bv[c].z + av[a].w * bv[c].w;
        }
        __syncthreads();
    }

    #pragma unroll
    for (int c = 0; c < 4; ++c) {
        float bo = b_out[oi + 16 * c];
        #pragma unroll
        for (int a = 0; a < 4; ++a)
            out[(size_t)(b * T_ + t0 + tg * 4 + a) * O_ + oi + 16 * c] =
                acc[a][c] + bo;
    }
}

// ---------------------------------------------------------------------------
extern "C" void kernel_launch(void* const* d_in, const int* in_sizes, int n_in,
                              void* d_out, int out_size, void* d_ws, size_t ws_size,
                              hipStream_t stream)
{
    const float* u     = (const float*)d_in[0];
    const float* x0    = (const float*)d_in[1];
    const float* noise = (const float*)d_in[2];
    const float* L     = (const float*)d_in[3];
    const float* M     = (const float*)d_in[4];
    const float* N     = (const float*)d_in[5];
    const float* W_in  = (const float*)d_in[6];
    const float* b_in  = (const float*)d_in[7];
    const float* W_out = (const float*)d_in[8];
    const float* b_out = (const float*)d_in[9];

    float* out   = (float*)d_out;                       // [B,T,O]
    float* xlast = out + (size_t)B_ * T_ * O_;          // [B,H]
    float* traj  = xlast + (size_t)B_ * H_;             // [B,T,H]

    // 1) inp -> traj region (consumed then overwritten in-place by the scan)
    inp_gemm<<<dim3(T_ / 64, H_ / 128, B_), 256, 0, stream>>>(u, W_in, b_in, traj);
    // 2) sequential scan, one block per batch
    scan_kernel<<<dim3(B_), 256, 0, stream>>>(noise, x0, L, M, N, traj, xlast);
    // 3) output projection
    out_gemm<<<dim3(T_ / 64, B_), 256, 0, stream>>>(traj, W_out, b_out, out);
}